// Round 7
// baseline (180.133 us; speedup 1.0000x reference)
//
#include <hip/hip_runtime.h>
#include <cstddef>
#include <cstdint>

#define NB 8
#define CIN 256
#define LL 1024
#define DKC 512
#define DVC 256
#define XPSTRIDE 295936  // 34*34*256

typedef short short8 __attribute__((ext_vector_type(8)));
typedef float f32x4 __attribute__((ext_vector_type(4)));

__device__ __forceinline__ unsigned short f2bf(float f) {
  unsigned int u = __float_as_uint(f);
  u += 0x7fffu + ((u >> 16) & 1u);
  return (unsigned short)(u >> 16);
}
__device__ __forceinline__ float bf2f(unsigned short u) {
  return __uint_as_float(((unsigned int)u) << 16);
}

// ------- fused weight/rel prep + xTp border zero (fp32 -> bf16) ----------
// q rows carry 1/8 (dkh^-0.5) AND log2(e) so attention can use exp2.
__global__ __launch_bounds__(256) void prep_weights(
    const float* __restrict__ wconv, const float* __restrict__ wqkv,
    const float* __restrict__ wout, const float* __restrict__ krh,
    const float* __restrict__ krw, unsigned short* __restrict__ wtap,
    unsigned short* __restrict__ wqbf, unsigned short* __restrict__ woutbf,
    unsigned short* __restrict__ relTh, unsigned short* __restrict__ relTw,
    unsigned short* __restrict__ xTp) {
  const int idx = blockIdx.x * 256 + threadIdx.x;
  if (idx < 589824) {
    const int tap = idx >> 16;
    const int rem = idx & 65535;
    wtap[idx] = f2bf(wconv[(size_t)rem * 9 + tap]);
  } else if (idx < 917504) {
    const int j = idx - 589824;
    const int o = j >> 8;
    const float sc = (o < DKC) ? 0.125f * 1.44269504088896f : 1.0f;
    wqbf[j] = f2bf(wqkv[j] * sc);
  } else if (idx < 983040) {
    const int j = idx - 917504;
    woutbf[j] = f2bf(wout[j]);
  } else if (idx < 991232) {
    const int j = idx - 983040;
    const int tbl = j >> 12;
    const int rest = j & 4095;
    const int m = rest >> 6, c = rest & 63;
    const float* src = tbl ? krw : krh;
    unsigned short* dst = tbl ? relTw : relTh;
    const float v = (m < 63) ? src[c * 63 + m] : 0.f;
    dst[m * 64 + c] = f2bf(v);
  } else {
    const int j2 = idx - 991232;  // border zero: 8*132*256
    const int b = j2 / 33792;
    const int rem = j2 - b * 33792;
    const int pos = rem >> 8, c = rem & 255;
    int hp, wp;
    if (pos < 34) { hp = 0; wp = pos; }
    else if (pos < 68) { hp = 33; wp = pos - 34; }
    else if (pos < 100) { hp = pos - 68 + 1; wp = 0; }
    else { hp = pos - 100 + 1; wp = 33; }
    xTp[(size_t)b * XPSTRIDE + (hp * 34 + wp) * 256 + c] = 0;
  }
}

// ---------------- x -> padded transposed bf16 [b][34][34][c] ----------
__global__ __launch_bounds__(256) void xpad_interior(
    const float* __restrict__ x, unsigned short* __restrict__ xTp) {
  __shared__ float tile[64][65];
  const int st = blockIdx.x;
  const int b = blockIdx.y;
  const int s0 = st * 64;
  const int h0 = st * 2;
  const int tid = threadIdx.x;
  for (int cc = 0; cc < 4; ++cc) {
    const int c0 = cc * 64;
    {
      const int row = tid >> 2;
      const int j0 = (tid & 3) * 16;
#pragma unroll
      for (int k = 0; k < 4; ++k)
        *(float4*)&tile[row][j0 + k * 4] =
            *(const float4*)(x + ((size_t)(b * CIN + c0 + row)) * LL + s0 + j0 + k * 4);
    }
    __syncthreads();
    {
      const int sl = tid >> 2;
      const int cb = (tid & 3) * 16;
      unsigned short buf[16];
#pragma unroll
      for (int m = 0; m < 16; ++m) buf[m] = f2bf(tile[cb + m][sl]);
      const int hp = h0 + (sl >> 5) + 1;
      const int wp = (sl & 31) + 1;
      unsigned short* dst = xTp + (size_t)b * XPSTRIDE + (hp * 34 + wp) * 256 + c0 + cb;
      *(uint4*)dst = *(uint4*)&buf[0];
      *(uint4*)(dst + 8) = *(uint4*)&buf[8];
    }
    __syncthreads();
  }
}

// ------- fused conv (ot<4) + qkv (ot>=4) implicit-GEMM bf16 MFMA ---------
__global__ __launch_bounds__(256) void convqkv_mfma(
    const unsigned short* __restrict__ xTp, const unsigned short* __restrict__ wtap,
    const unsigned short* __restrict__ wqbf, float* __restrict__ out,
    unsigned short* __restrict__ qbf, unsigned short* __restrict__ kbf,
    unsigned short* __restrict__ vbf) {
  __shared__ __align__(16) unsigned short as[64 * 64];
  __shared__ __align__(16) unsigned short bs[64 * 64];
  __shared__ float trans[64][65];
  const int tid = threadIdx.x;
  const int lane = tid & 63, w = tid >> 6;
  const int n16 = lane & 15, quad = lane >> 4;
  const int otg = blockIdx.x;  // 0..23: 0-3 conv, 4-23 qkv
  const int st = blockIdx.y;
  const int b = blockIdx.z;
  const int s0 = st * 64;
  const int h0 = st * 2;
  const int trow = tid >> 3, ck = tid & 7;

  const unsigned short* xb = xTp + (size_t)b * XPSTRIDE;

  f32x4 acc[4];
#pragma unroll
  for (int nt = 0; nt < 4; ++nt) acc[nt] = (f32x4){0.f, 0.f, 0.f, 0.f};

  if (otg < 4) {
    // ---- conv: 9 taps x 4 c-chunks ----
    const int ot = otg;
    const unsigned short* wbase = wtap + (size_t)(ot * 64) * 256;
    uint4 ra0, ra1, rb0, rb1;
    auto loadtile = [&](int it) {
      const int tap = it >> 2;
      const int c0 = (it & 3) * 64;
      const int dh = tap / 3 - 1;
      const int dw = tap - (tap / 3) * 3 - 1;
      const unsigned short* wt = wbase + (size_t)tap * 65536;
      ra0 = *(const uint4*)(wt + (size_t)trow * 256 + c0 + ck * 8);
      ra1 = *(const uint4*)(wt + (size_t)(trow + 32) * 256 + c0 + ck * 8);
      const int wp = (trow & 31) + dw + 1;
      rb0 = *(const uint4*)(xb + (size_t)((h0 + dh + 1) * 34 + wp) * 256 + c0 + ck * 8);
      rb1 = *(const uint4*)(xb + (size_t)((h0 + dh + 2) * 34 + wp) * 256 + c0 + ck * 8);
    };
    loadtile(0);
    for (int it = 0; it < 36; ++it) {
      __syncthreads();
      *(uint4*)&as[trow * 64 + ((ck ^ (trow & 7)) * 8)] = ra0;
      *(uint4*)&as[(trow + 32) * 64 + ((ck ^ (trow & 7)) * 8)] = ra1;
      *(uint4*)&bs[trow * 64 + ((ck ^ (trow & 7)) * 8)] = rb0;
      *(uint4*)&bs[(trow + 32) * 64 + ((ck ^ (trow & 7)) * 8)] = rb1;
      __syncthreads();
      if (it < 35) loadtile(it + 1);
      short8 a0 = *(const short8*)&as[(w * 16 + n16) * 64 + ((quad ^ (n16 & 7)) * 8)];
      short8 a1 = *(const short8*)&as[(w * 16 + n16) * 64 + (((quad + 4) ^ (n16 & 7)) * 8)];
#pragma unroll
      for (int nt = 0; nt < 4; ++nt) {
        short8 b0 = *(const short8*)&bs[(nt * 16 + n16) * 64 + ((quad ^ (n16 & 7)) * 8)];
        short8 b1 = *(const short8*)&bs[(nt * 16 + n16) * 64 + (((quad + 4) ^ (n16 & 7)) * 8)];
        acc[nt] = __builtin_amdgcn_mfma_f32_16x16x32_bf16(a0, b0, acc[nt], 0, 0, 0);
        acc[nt] = __builtin_amdgcn_mfma_f32_16x16x32_bf16(a1, b1, acc[nt], 0, 0, 0);
      }
    }
#pragma unroll
    for (int nt = 0; nt < 4; ++nt)
#pragma unroll
      for (int reg = 0; reg < 4; ++reg)
        out[((size_t)b * 512 + ot * 64 + w * 16 + quad * 4 + reg) * LL + s0 + nt * 16 + n16] =
            acc[nt][reg];
  } else {
    // ---- qkv: 4 c-chunks, epilogue relayout ----
    const int ot = otg - 4;  // 0..19
    const unsigned short* wt = wqbf + (size_t)(ot * 64) * 256;
    const int wpos = (trow & 31) + 1;
    uint4 ra0, ra1, rb0, rb1;
    ra0 = *(const uint4*)(wt + (size_t)trow * 256 + ck * 8);
    ra1 = *(const uint4*)(wt + (size_t)(trow + 32) * 256 + ck * 8);
    rb0 = *(const uint4*)(xb + (size_t)((h0 + 1) * 34 + wpos) * 256 + ck * 8);
    rb1 = *(const uint4*)(xb + (size_t)((h0 + 2) * 34 + wpos) * 256 + ck * 8);
#pragma unroll
    for (int kc = 0; kc < 4; ++kc) {
      __syncthreads();
      *(uint4*)&as[trow * 64 + ((ck ^ (trow & 7)) * 8)] = ra0;
      *(uint4*)&as[(trow + 32) * 64 + ((ck ^ (trow & 7)) * 8)] = ra1;
      *(uint4*)&bs[trow * 64 + ((ck ^ (trow & 7)) * 8)] = rb0;
      *(uint4*)&bs[(trow + 32) * 64 + ((ck ^ (trow & 7)) * 8)] = rb1;
      __syncthreads();
      if (kc < 3) {
        const int c0 = (kc + 1) * 64;
        ra0 = *(const uint4*)(wt + (size_t)trow * 256 + c0 + ck * 8);
        ra1 = *(const uint4*)(wt + (size_t)(trow + 32) * 256 + c0 + ck * 8);
        rb0 = *(const uint4*)(xb + (size_t)((h0 + 1) * 34 + wpos) * 256 + c0 + ck * 8);
        rb1 = *(const uint4*)(xb + (size_t)((h0 + 2) * 34 + wpos) * 256 + c0 + ck * 8);
      }
      short8 a0 = *(const short8*)&as[(w * 16 + n16) * 64 + ((quad ^ (n16 & 7)) * 8)];
      short8 a1 = *(const short8*)&as[(w * 16 + n16) * 64 + (((quad + 4) ^ (n16 & 7)) * 8)];
#pragma unroll
      for (int nt = 0; nt < 4; ++nt) {
        short8 b0 = *(const short8*)&bs[(nt * 16 + n16) * 64 + ((quad ^ (n16 & 7)) * 8)];
        short8 b1 = *(const short8*)&bs[(nt * 16 + n16) * 64 + (((quad + 4) ^ (n16 & 7)) * 8)];
        acc[nt] = __builtin_amdgcn_mfma_f32_16x16x32_bf16(a0, b0, acc[nt], 0, 0, 0);
        acc[nt] = __builtin_amdgcn_mfma_f32_16x16x32_bf16(a1, b1, acc[nt], 0, 0, 0);
      }
    }
    __syncthreads();
#pragma unroll
    for (int nt = 0; nt < 4; ++nt)
#pragma unroll
      for (int reg = 0; reg < 4; ++reg)
        trans[w * 16 + quad * 4 + reg][nt * 16 + n16] = acc[nt][reg];
    __syncthreads();
    const int sl = tid >> 2;
    const int cseg = (tid & 3) * 16;
    unsigned short buf[16];
    if (ot < 16) {
#pragma unroll
      for (int m = 0; m < 16; ++m) buf[m] = f2bf(trans[cseg + m][sl]);
      unsigned short* dst;
      int head;
      if (ot < 8) { dst = qbf; head = ot; }
      else { dst = kbf; head = ot - 8; }
      const size_t base = (((size_t)(b * 8 + head)) * LL + s0 + sl) * 64 + cseg;
      *(uint4*)(dst + base) = *(uint4*)&buf[0];
      *(uint4*)(dst + base + 8) = *(uint4*)&buf[8];
    } else {
#pragma unroll
      for (int m = 0; m < 16; ++m) buf[m] = f2bf(trans[sl][cseg + m]);
      unsigned short* dst = vbf + ((size_t)b * DVC + (ot - 16) * 64 + sl) * LL + s0 + cseg;
      *(uint4*)dst = *(uint4*)&buf[0];
      *(uint4*)(dst + 8) = *(uint4*)&buf[8];
    }
  }
}

// ------- MFMA flash attention, 128 q-rows/block, fixed-max softmax -------
// grid 512: bn = blk&63 (head/batch -> XCD locality), qt = blk>>6 (8 tiles).
__global__ __launch_bounds__(256, 2) void attn_kernel(
    const unsigned short* __restrict__ qbf, const unsigned short* __restrict__ kbf,
    const unsigned short* __restrict__ vbf, const unsigned short* __restrict__ relTh,
    const unsigned short* __restrict__ relTw, unsigned short* __restrict__ abf) {
  __shared__ __align__(16) char smem[45056];
  unsigned short* ks = (unsigned short*)smem;             // [64 key][64 c] swizzled
  unsigned short* vs = (unsigned short*)(smem + 8192);    // [32 cv][64 key] swizzled
  unsigned short* ps = (unsigned short*)(smem + 12288);   // [128 q][64 key]; rh transient
  unsigned short* rwtT = (unsigned short*)(smem + 28672); // [64 m][128 row] swizzled
  float* obuf = (float*)smem;                             // [128][33] fp32 overlay

  const int tid = threadIdx.x;
  const int lane = tid & 63, w = tid >> 6;
  const int n16 = lane & 15, quad = lane >> 4;
  const int blk = blockIdx.x;
  const int bn = blk & 63, qt = blk >> 6;
  const int n = bn & 7, b = bn >> 3;
  const int s0 = qt * 128;
  const int pb = (w & 1) * 16;
  const int aar[2] = {4 * qt + (w >> 1), 4 * qt + 2 + (w >> 1)};

  const unsigned short* qbase = qbf + ((size_t)(b * 8 + n)) * LL * 64;
  const unsigned short* kbase = kbf + ((size_t)(b * 8 + n)) * LL * 64;
  const unsigned short* vbase = vbf + ((size_t)(b * 8 + n)) * 32 * LL;

  const int ck = tid & 7;
  const int trow = tid >> 3;

  // prefetch K/V tile 0 (in flight during prologue)
  uint4 pk0 = *(const uint4*)(kbase + trow * 64 + ck * 8);
  uint4 pk1 = *(const uint4*)(kbase + (trow + 32) * 64 + ck * 8);
  uint4 pv = *(const uint4*)(vbase + (size_t)trow * LL + ck * 8);

  // ---- prologue: rel tables via MFMA for both row-sets ----
#pragma unroll
  for (int rs = 0; rs < 2; ++rs) {
    const int aa = aar[rs];
    const int sT = (pb + n16) * 32 + aa;
    short8 ra0 = *(const short8*)(qbase + (size_t)sT * 64 + quad * 8);
    short8 ra1 = *(const short8*)(qbase + (size_t)sT * 64 + 32 + quad * 8);
#pragma unroll
    for (int tbl = 0; tbl < 2; ++tbl) {
      const unsigned short* rel = tbl ? relTh : relTw;
      f32x4 acc[4];
#pragma unroll
      for (int mt = 0; mt < 4; ++mt) acc[mt] = (f32x4){0.f, 0.f, 0.f, 0.f};
#pragma unroll
      for (int mt = 0; mt < 4; ++mt) {
        short8 b0 = *(const short8*)(rel + (mt * 16 + n16) * 64 + quad * 8);
        short8 b1 = *(const short8*)(rel + (mt * 16 + n16) * 64 + 32 + quad * 8);
        acc[mt] = __builtin_amdgcn_mfma_f32_16x16x32_bf16(ra0, b0, acc[mt], 0, 0, 0);
        acc[mt] = __builtin_amdgcn_mfma_f32_16x16x32_bf16(ra1, b1, acc[mt], 0, 0, 0);
      }
      if (tbl == 0) {
#pragma unroll
        for (int mt = 0; mt < 4; ++mt)
#pragma unroll
          for (int reg = 0; reg < 4; ++reg)
            rwtT[(mt * 16 + n16) * 128 +
                 ((rs * 64 + w * 16 + quad * 4 + reg) ^ ((n16 & 7) * 8))] = f2bf(acc[mt][reg]);
      } else {
#pragma unroll
        for (int mt = 0; mt < 4; ++mt)
#pragma unroll
          for (int reg = 0; reg < 4; ++reg)
            ps[(rs * 64 + w * 16 + quad * 4 + reg) * 64 + mt * 16 + n16] = f2bf(acc[mt][reg]);
      }
    }
  }
  short8 qf[2][2];
#pragma unroll
  for (int rs = 0; rs < 2; ++rs) {
    const size_t qrow = (size_t)(s0 + rs * 64 + w * 16 + n16) * 64;
    qf[rs][0] = *(const short8*)(qbase + qrow + quad * 8);
    qf[rs][1] = *(const short8*)(qbase + qrow + 32 + quad * 8);
  }
  __syncthreads();
  // hoist rh bias (kt-invariant) into registers; ps region is wave-private
  float rhreg[2][2][4];
#pragma unroll
  for (int rs = 0; rs < 2; ++rs)
#pragma unroll
    for (int tt1 = 0; tt1 < 2; ++tt1)
#pragma unroll
      for (int reg = 0; reg < 4; ++reg) {
        const int iL = quad * 4 + reg;
        rhreg[rs][tt1][reg] =
            bf2f(ps[(rs * 64 + w * 16 + iL) * 64 + tt1 * 16 + n16 + 31 - pb - iL]);
      }

  float lacc[2][4] = {};
  f32x4 oacc[2][2];
#pragma unroll
  for (int rs = 0; rs < 2; ++rs)
#pragma unroll
    for (int ct = 0; ct < 2; ++ct) oacc[rs][ct] = (f32x4){0.f, 0.f, 0.f, 0.f};

  const int rbq = w * 16 + quad * 4;

  for (int kt64 = 0; kt64 < 16; ++kt64) {
    const int t0 = kt64 * 64;
    __syncthreads();
    *(uint4*)&ks[trow * 64 + ((ck ^ (trow & 7)) * 8)] = pk0;
    *(uint4*)&ks[(trow + 32) * 64 + ((ck ^ (trow & 7)) * 8)] = pk1;
    *(uint4*)&vs[trow * 64 + ((ck ^ (trow & 7)) * 8)] = pv;
    __syncthreads();
    if (kt64 < 15) {
      const unsigned short* kg = kbase + (size_t)(t0 + 64) * 64;
      pk0 = *(const uint4*)(kg + trow * 64 + ck * 8);
      pk1 = *(const uint4*)(kg + (trow + 32) * 64 + ck * 8);
      pv = *(const uint4*)(vbase + (size_t)trow * LL + t0 + 64 + ck * 8);
    }

    // QK^T: K-frags shared across both row-sets
    f32x4 sacc[2][4];
#pragma unroll
    for (int rs = 0; rs < 2; ++rs)
#pragma unroll
      for (int tt = 0; tt < 4; ++tt) sacc[rs][tt] = (f32x4){0.f, 0.f, 0.f, 0.f};
#pragma unroll
    for (int tt = 0; tt < 4; ++tt) {
      short8 kb0 = *(const short8*)&ks[(tt * 16 + n16) * 64 + ((quad ^ (n16 & 7)) * 8)];
      short8 kb1 = *(const short8*)&ks[(tt * 16 + n16) * 64 + (((quad + 4) ^ (n16 & 7)) * 8)];
#pragma unroll
      for (int rs = 0; rs < 2; ++rs) {
        sacc[rs][tt] = __builtin_amdgcn_mfma_f32_16x16x32_bf16(qf[rs][0], kb0, sacc[rs][tt], 0, 0, 0);
        sacc[rs][tt] = __builtin_amdgcn_mfma_f32_16x16x32_bf16(qf[rs][1], kb1, sacc[rs][tt], 0, 0, 0);
      }
    }
    // rw bias: mw wave-uniform per (rs,h) -> b64 broadcast reads
    float rwv[2][2][4];
#pragma unroll
    for (int rs = 0; rs < 2; ++rs)
#pragma unroll
      for (int h = 0; h < 2; ++h) {
        const int mw = (t0 >> 5) + h - aar[rs] + 31;
        const ushort4 rw4 =
            *(const ushort4*)&rwtT[mw * 128 + ((rs * 64 + rbq) ^ ((mw & 7) * 8))];
        rwv[rs][h][0] = bf2f(rw4.x); rwv[rs][h][1] = bf2f(rw4.y);
        rwv[rs][h][2] = bf2f(rw4.z); rwv[rs][h][3] = bf2f(rw4.w);
      }
    // P = exp2(s + rw + rh); RTZ bf16 store into wave-private region
#pragma unroll
    for (int rs = 0; rs < 2; ++rs)
#pragma unroll
      for (int tt = 0; tt < 4; ++tt)
#pragma unroll
        for (int reg = 0; reg < 4; ++reg) {
          const float e = __builtin_amdgcn_exp2f(sacc[rs][tt][reg] + rwv[rs][tt >> 1][reg] +
                                                 rhreg[rs][tt & 1][reg]);
          lacc[rs][reg] += e;
          const int r = quad * 4 + reg;
          ps[(rs * 64 + w * 16 + r) * 64 + (((tt * 2 + (n16 >> 3)) ^ (r & 7)) * 8) + (n16 & 7)] =
              (unsigned short)(__float_as_uint(e) >> 16);
        }
    __asm__ volatile("s_waitcnt lgkmcnt(0)" ::: "memory");
    // P @ V: V-frags shared across both row-sets
#pragma unroll
    for (int kt = 0; kt < 2; ++kt) {
      short8 pa[2];
#pragma unroll
      for (int rs = 0; rs < 2; ++rs)
        pa[rs] = *(const short8*)&ps[(rs * 64 + w * 16 + n16) * 64 +
                                     (((quad + 4 * kt) ^ (n16 & 7)) * 8)];
#pragma unroll
      for (int ct = 0; ct < 2; ++ct) {
        short8 vb = *(const short8*)&vs[(ct * 16 + n16) * 64 + (((quad + 4 * kt) ^ (n16 & 7)) * 8)];
#pragma unroll
        for (int rs = 0; rs < 2; ++rs)
          oacc[rs][ct] = __builtin_amdgcn_mfma_f32_16x16x32_bf16(pa[rs], vb, oacc[rs][ct], 0, 0, 0);
      }
    }
  }
  // deferred row-sum reduction
  float linv[2][4];
#pragma unroll
  for (int rs = 0; rs < 2; ++rs)
#pragma unroll
    for (int reg = 0; reg < 4; ++reg) {
      float l = lacc[rs][reg];
#pragma unroll
      for (int m = 1; m < 16; m <<= 1) l += __shfl_xor(l, m, 16);
      linv[rs][reg] = 1.0f / l;
    }
  __syncthreads();
#pragma unroll
  for (int rs = 0; rs < 2; ++rs)
#pragma unroll
    for (int ct = 0; ct < 2; ++ct)
#pragma unroll
      for (int reg = 0; reg < 4; ++reg)
        obuf[(rs * 64 + w * 16 + quad * 4 + reg) * 33 + ct * 16 + n16] =
            oacc[rs][ct][reg] * linv[rs][reg];
  __syncthreads();
  {
    const int row = tid >> 1;            // 0..127
    const int cseg = (tid & 1) * 16;     // cv chunk
    unsigned short buf16[16];
#pragma unroll
    for (int m = 0; m < 16; ++m) buf16[m] = f2bf(obuf[row * 33 + cseg + m]);
    unsigned short* dst = abf + (((size_t)b * LL) + s0 + row) * 256 + n * 32 + cseg;
    *(uint4*)dst = *(uint4*)&buf16[0];
    *(uint4*)(dst + 8) = *(uint4*)&buf16[8];
  }
}

// ---------------- output projection as bf16 MFMA GEMM ----------------
__global__ __launch_bounds__(256) void proj_mfma(
    const unsigned short* __restrict__ abf, const unsigned short* __restrict__ woutbf,
    float* __restrict__ out) {
  __shared__ __align__(16) unsigned short as[64 * 64];
  __shared__ __align__(16) unsigned short bs[64 * 64];
  const int tid = threadIdx.x;
  const int lane = tid & 63, w = tid >> 6;
  const int n16 = lane & 15, quad = lane >> 4;
  const int ot = blockIdx.x;
  const int st = blockIdx.y;
  const int b = blockIdx.z;
  const int o0 = ot * 64;
  const int s0 = st * 64;
  const int trow = tid >> 3, ck = tid & 7;

  const unsigned short* ab = abf + ((size_t)b * LL + s0) * 256;
  const unsigned short* wt = woutbf + (size_t)o0 * 256;

  f32x4 acc[4];
#pragma unroll
  for (int nt = 0; nt < 4; ++nt) acc[nt] = (f32x4){0.f, 0.f, 0.f, 0.f};

  uint4 ra0, ra1, rb0, rb1;
  ra0 = *(const uint4*)(wt + (size_t)trow * 256 + ck * 8);
  ra1 = *(const uint4*)(wt + (size_t)(trow + 32) * 256 + ck * 8);
  rb0 = *(const uint4*)(ab + (size_t)trow * 256 + ck * 8);
  rb1 = *(const uint4*)(ab + (size_t)(trow + 32) * 256 + ck * 8);
#pragma unroll
  for (int kc = 0; kc < 4; ++kc) {
    __syncthreads();
    *(uint4*)&as[trow * 64 + ((ck ^ (trow & 7)) * 8)] = ra0;
    *(uint4*)&as[(trow + 32) * 64 + ((ck ^ (trow & 7)) * 8)] = ra1;
    *(uint4*)&bs[trow * 64 + ((ck ^ (trow & 7)) * 8)] = rb0;
    *(uint4*)&bs[(trow + 32) * 64 + ((ck ^ (trow & 7)) * 8)] = rb1;
    __syncthreads();
    if (kc < 3) {
      const int c0 = (kc + 1) * 64;
      ra0 = *(const uint4*)(wt + (size_t)trow * 256 + c0 + ck * 8);
      ra1 = *(const uint4*)(wt + (size_t)(trow + 32) * 256 + c0 + ck * 8);
      rb0 = *(const uint4*)(ab + (size_t)trow * 256 + c0 + ck * 8);
      rb1 = *(const uint4*)(ab + (size_t)(trow + 32) * 256 + c0 + ck * 8);
    }
    short8 a0 = *(const short8*)&as[(w * 16 + n16) * 64 + ((quad ^ (n16 & 7)) * 8)];
    short8 a1 = *(const short8*)&as[(w * 16 + n16) * 64 + (((quad + 4) ^ (n16 & 7)) * 8)];
#pragma unroll
    for (int nt = 0; nt < 4; ++nt) {
      short8 b0 = *(const short8*)&bs[(nt * 16 + n16) * 64 + ((quad ^ (n16 & 7)) * 8)];
      short8 b1 = *(const short8*)&bs[(nt * 16 + n16) * 64 + (((quad + 4) ^ (n16 & 7)) * 8)];
      acc[nt] = __builtin_amdgcn_mfma_f32_16x16x32_bf16(a0, b0, acc[nt], 0, 0, 0);
      acc[nt] = __builtin_amdgcn_mfma_f32_16x16x32_bf16(a1, b1, acc[nt], 0, 0, 0);
    }
  }
#pragma unroll
  for (int nt = 0; nt < 4; ++nt)
#pragma unroll
    for (int reg = 0; reg < 4; ++reg)
      out[((size_t)b * 512 + 256 + o0 + w * 16 + quad * 4 + reg) * LL + s0 + nt * 16 + n16] =
          acc[nt][reg];
}

extern "C" void kernel_launch(void* const* d_in, const int* in_sizes, int n_in,
                              void* d_out, int out_size, void* d_ws, size_t ws_size,
                              hipStream_t stream) {
  const float* x     = (const float*)d_in[0];
  const float* wqkv  = (const float*)d_in[1];
  const float* wconv = (const float*)d_in[2];
  const float* wout  = (const float*)d_in[3];
  const float* krh   = (const float*)d_in[4];
  const float* krw   = (const float*)d_in[5];
  float* out = (float*)d_out;

  unsigned short* qbf = (unsigned short*)d_ws;
  unsigned short* kbf = qbf + (size_t)NB * 8 * LL * 64;
  unsigned short* vbf = kbf + (size_t)NB * 8 * LL * 64;
  unsigned short* abf = vbf + (size_t)NB * DVC * LL;
  unsigned short* relTh = abf + (size_t)NB * LL * DVC;
  unsigned short* relTw = relTh + 4096;
  unsigned short* xTp = relTw + 4096;
  unsigned short* wtap = xTp + (size_t)NB * XPSTRIDE;
  unsigned short* wqbf = wtap + 589824;
  unsigned short* woutbf = wqbf + 327680;

  prep_weights<<<dim3(4928), 256, 0, stream>>>(wconv, wqkv, wout, krh, krw,
                                               wtap, wqbf, woutbf, relTh, relTw, xTp);
  xpad_interior<<<dim3(16, 8), 256, 0, stream>>>(x, xTp);
  convqkv_mfma<<<dim3(24, 16, NB), 256, 0, stream>>>(xTp, wtap, wqbf, out, qbf, kbf, vbf);
  attn_kernel<<<dim3(512), 256, 0, stream>>>(qbf, kbf, vbf, relTh, relTw, abf);
  proj_mfma<<<dim3(4, 16, NB), 256, 0, stream>>>(abf, woutbf, out);
}

// Round 8
// 162.721 us; speedup vs baseline: 1.1070x; 1.1070x over previous
//
#include <hip/hip_runtime.h>
#include <cstddef>
#include <cstdint>

#define NB 8
#define CIN 256
#define LL 1024
#define DKC 512
#define DVC 256
#define XPSTRIDE 295936  // 34*34*256

typedef short short8 __attribute__((ext_vector_type(8)));
typedef float f32x4 __attribute__((ext_vector_type(4)));

__device__ __forceinline__ unsigned short f2bf(float f) {
  unsigned int u = __float_as_uint(f);
  u += 0x7fffu + ((u >> 16) & 1u);
  return (unsigned short)(u >> 16);
}
__device__ __forceinline__ float bf2f(unsigned short u) {
  return __uint_as_float(((unsigned int)u) << 16);
}

// ------- fused weight/rel prep + xTp border zero (fp32 -> bf16) ----------
// Weights are emitted in A-FRAGMENT order [tile][kchunk][row 64][k 64] so
// GEMM kernels load A-frags directly from global (L2) with no LDS staging.
// q rows carry 1/8 (dkh^-0.5) AND log2(e) so attention can use exp2.
__global__ __launch_bounds__(256) void prep_weights(
    const float* __restrict__ wconv, const float* __restrict__ wqkv,
    const float* __restrict__ wout, const float* __restrict__ krh,
    const float* __restrict__ krw, unsigned short* __restrict__ wtap,
    unsigned short* __restrict__ wqbf, unsigned short* __restrict__ woutbf,
    unsigned short* __restrict__ relTh, unsigned short* __restrict__ relTw,
    unsigned short* __restrict__ xTp) {
  const int idx = blockIdx.x * 256 + threadIdx.x;
  if (idx < 589824) {
    // wtap layout: [ot 4][tap 9][kc 4][row 64][kin 64]
    const int g = idx >> 14;           // ot*9+tap
    const int ot = g / 9, tap = g - ot * 9;
    const int rem2 = idx & 16383;
    const int kc = rem2 >> 12;
    const int row = (rem2 >> 6) & 63, kin = rem2 & 63;
    const int o = ot * 64 + row, c = kc * 64 + kin;
    wtap[idx] = f2bf(wconv[(size_t)(o * 256 + c) * 9 + tap]);
  } else if (idx < 917504) {
    // wqbf layout: [ot 20][kc 4][row 64][kin 64]
    const int j = idx - 589824;
    const int g = j >> 12;             // ot*4+kc
    const int ot = g >> 2, kc = g & 3;
    const int row = (j >> 6) & 63, kin = j & 63;
    const int o = ot * 64 + row, c = kc * 64 + kin;
    const float sc = (o < DKC) ? 0.125f * 1.44269504088896f : 1.0f;
    wqbf[j] = f2bf(wqkv[o * 256 + c] * sc);
  } else if (idx < 983040) {
    // woutbf layout: [ot 4][kc 4][row 64][kin 64]
    const int j = idx - 917504;
    const int g = j >> 12;
    const int o = (g >> 2) * 64 + ((j >> 6) & 63);
    const int c = (g & 3) * 64 + (j & 63);
    woutbf[j] = f2bf(wout[o * 256 + c]);
  } else if (idx < 991232) {
    const int j = idx - 983040;
    const int tbl = j >> 12;
    const int rest = j & 4095;
    const int m = rest >> 6, c = rest & 63;
    const float* src = tbl ? krw : krh;
    unsigned short* dst = tbl ? relTw : relTh;
    const float v = (m < 63) ? src[c * 63 + m] : 0.f;
    dst[m * 64 + c] = f2bf(v);
  } else {
    const int j2 = idx - 991232;  // border zero: 8*132*256
    const int b = j2 / 33792;
    const int rem = j2 - b * 33792;
    const int pos = rem >> 8, c = rem & 255;
    int hp, wp;
    if (pos < 34) { hp = 0; wp = pos; }
    else if (pos < 68) { hp = 33; wp = pos - 34; }
    else if (pos < 100) { hp = pos - 68 + 1; wp = 0; }
    else { hp = pos - 100 + 1; wp = 33; }
    xTp[(size_t)b * XPSTRIDE + (hp * 34 + wp) * 256 + c] = 0;
  }
}

// ---------------- x -> padded transposed bf16 [b][34][34][c] ----------
__global__ __launch_bounds__(256) void xpad_interior(
    const float* __restrict__ x, unsigned short* __restrict__ xTp) {
  __shared__ float tile[64][65];
  const int st = blockIdx.x;
  const int b = blockIdx.y;
  const int s0 = st * 64;
  const int h0 = st * 2;
  const int tid = threadIdx.x;
  for (int cc = 0; cc < 4; ++cc) {
    const int c0 = cc * 64;
    {
      const int row = tid >> 2;
      const int j0 = (tid & 3) * 16;
#pragma unroll
      for (int k = 0; k < 4; ++k)
        *(float4*)&tile[row][j0 + k * 4] =
            *(const float4*)(x + ((size_t)(b * CIN + c0 + row)) * LL + s0 + j0 + k * 4);
    }
    __syncthreads();
    {
      const int sl = tid >> 2;
      const int cb = (tid & 3) * 16;
      unsigned short buf[16];
#pragma unroll
      for (int m = 0; m < 16; ++m) buf[m] = f2bf(tile[cb + m][sl]);
      const int hp = h0 + (sl >> 5) + 1;
      const int wp = (sl & 31) + 1;
      unsigned short* dst = xTp + (size_t)b * XPSTRIDE + (hp * 34 + wp) * 256 + c0 + cb;
      *(uint4*)dst = *(uint4*)&buf[0];
      *(uint4*)(dst + 8) = *(uint4*)&buf[8];
    }
    __syncthreads();
  }
}

// ------- QKV projection: A-frags direct from global, B staged in LDS -----
__global__ __launch_bounds__(256) void qkv_mfma(
    const unsigned short* __restrict__ xTp, const unsigned short* __restrict__ wqbf,
    unsigned short* __restrict__ qbf, unsigned short* __restrict__ kbf,
    unsigned short* __restrict__ vbf) {
  __shared__ __align__(16) char qsmem[16640];  // bs (8KB) then trans overlay
  unsigned short* bs = (unsigned short*)qsmem;
  float (*trans)[65] = (float(*)[65])qsmem;
  const int tid = threadIdx.x;
  const int lane = tid & 63, w = tid >> 6;
  const int n16 = lane & 15, quad = lane >> 4;
  const int ot = blockIdx.x;   // 0..19
  const int st = blockIdx.y;   // 0..15
  const int b = blockIdx.z;
  const int s0 = st * 64;
  const int h0 = st * 2;
  const int trow = tid >> 3, ck = tid & 7;

  const unsigned short* xb = xTp + (size_t)b * XPSTRIDE;
  const unsigned short* wA = wqbf + (size_t)ot * 16384 + (w * 16 + n16) * 64 + quad * 8;
  const int wpos = (trow & 31) + 1;

  f32x4 acc[4];
#pragma unroll
  for (int nt = 0; nt < 4; ++nt) acc[nt] = (f32x4){0.f, 0.f, 0.f, 0.f};

  uint4 rb0 = *(const uint4*)(xb + (size_t)((h0 + 1) * 34 + wpos) * 256 + ck * 8);
  uint4 rb1 = *(const uint4*)(xb + (size_t)((h0 + 2) * 34 + wpos) * 256 + ck * 8);
  short8 af0 = *(const short8*)(wA);
  short8 af1 = *(const short8*)(wA + 32);
#pragma unroll
  for (int kc = 0; kc < 4; ++kc) {
    __syncthreads();
    *(uint4*)&bs[trow * 64 + ((ck ^ (trow & 7)) * 8)] = rb0;
    *(uint4*)&bs[(trow + 32) * 64 + ((ck ^ (trow & 7)) * 8)] = rb1;
    __syncthreads();
    short8 a0 = af0, a1 = af1;
    if (kc < 3) {
      const int c0 = (kc + 1) * 64;
      rb0 = *(const uint4*)(xb + (size_t)((h0 + 1) * 34 + wpos) * 256 + c0 + ck * 8);
      rb1 = *(const uint4*)(xb + (size_t)((h0 + 2) * 34 + wpos) * 256 + c0 + ck * 8);
      af0 = *(const short8*)(wA + (kc + 1) * 4096);
      af1 = *(const short8*)(wA + (kc + 1) * 4096 + 32);
    }
#pragma unroll
    for (int nt = 0; nt < 4; ++nt) {
      short8 b0 = *(const short8*)&bs[(nt * 16 + n16) * 64 + ((quad ^ (n16 & 7)) * 8)];
      short8 b1 = *(const short8*)&bs[(nt * 16 + n16) * 64 + (((quad + 4) ^ (n16 & 7)) * 8)];
      acc[nt] = __builtin_amdgcn_mfma_f32_16x16x32_bf16(a0, b0, acc[nt], 0, 0, 0);
      acc[nt] = __builtin_amdgcn_mfma_f32_16x16x32_bf16(a1, b1, acc[nt], 0, 0, 0);
    }
  }
  __syncthreads();
#pragma unroll
  for (int nt = 0; nt < 4; ++nt)
#pragma unroll
    for (int reg = 0; reg < 4; ++reg)
      trans[w * 16 + quad * 4 + reg][nt * 16 + n16] = acc[nt][reg];
  __syncthreads();
  const int sl = tid >> 2;
  const int cseg = (tid & 3) * 16;
  unsigned short buf[16];
  if (ot < 16) {
#pragma unroll
    for (int m = 0; m < 16; ++m) buf[m] = f2bf(trans[cseg + m][sl]);
    unsigned short* dst;
    int head;
    if (ot < 8) { dst = qbf; head = ot; }
    else { dst = kbf; head = ot - 8; }
    const size_t base = (((size_t)(b * 8 + head)) * LL + s0 + sl) * 64 + cseg;
    *(uint4*)(dst + base) = *(uint4*)&buf[0];
    *(uint4*)(dst + base + 8) = *(uint4*)&buf[8];
  } else {
#pragma unroll
    for (int m = 0; m < 16; ++m) buf[m] = f2bf(trans[sl][cseg + m]);
    unsigned short* dst = vbf + ((size_t)b * DVC + (ot - 16) * 64 + sl) * LL + s0 + cseg;
    *(uint4*)dst = *(uint4*)&buf[0];
    *(uint4*)(dst + 8) = *(uint4*)&buf[8];
  }
}

// ------- conv implicit GEMM: A-frags direct from global, B in LDS --------
__global__ __launch_bounds__(256) void conv_mfma(
    const unsigned short* __restrict__ xTp, const unsigned short* __restrict__ wtap,
    float* __restrict__ out) {
  __shared__ __align__(16) unsigned short bs[64 * 64];
  const int tid = threadIdx.x;
  const int lane = tid & 63, w = tid >> 6;
  const int n16 = lane & 15, quad = lane >> 4;
  const int ot = blockIdx.x;
  const int st = blockIdx.y;
  const int b = blockIdx.z;
  const int s0 = st * 64;
  const int h0 = st * 2;
  const int trow = tid >> 3;
  const int ck = tid & 7;

  const unsigned short* xb = xTp + (size_t)b * XPSTRIDE;
  // wtap frag-order: [ot][it=tap*4+kc][row][kin]
  const unsigned short* wA = wtap + (size_t)ot * 147456 + (w * 16 + n16) * 64 + quad * 8;

  f32x4 acc[4];
#pragma unroll
  for (int nt = 0; nt < 4; ++nt) acc[nt] = (f32x4){0.f, 0.f, 0.f, 0.f};

  uint4 rb0, rb1;
  auto loadB = [&](int it) {
    const int tap = it >> 2;
    const int c0 = (it & 3) * 64;
    const int dh = tap / 3 - 1;
    const int dw = tap - (tap / 3) * 3 - 1;
    const int wp = (trow & 31) + dw + 1;
    rb0 = *(const uint4*)(xb + (size_t)((h0 + dh + 1) * 34 + wp) * 256 + c0 + ck * 8);
    rb1 = *(const uint4*)(xb + (size_t)((h0 + dh + 2) * 34 + wp) * 256 + c0 + ck * 8);
  };
  loadB(0);
  short8 af0 = *(const short8*)(wA);
  short8 af1 = *(const short8*)(wA + 32);
  for (int it = 0; it < 36; ++it) {
    __syncthreads();
    *(uint4*)&bs[trow * 64 + ((ck ^ (trow & 7)) * 8)] = rb0;
    *(uint4*)&bs[(trow + 32) * 64 + ((ck ^ (trow & 7)) * 8)] = rb1;
    __syncthreads();
    short8 a0 = af0, a1 = af1;
    if (it < 35) {
      loadB(it + 1);
      af0 = *(const short8*)(wA + (size_t)(it + 1) * 4096);
      af1 = *(const short8*)(wA + (size_t)(it + 1) * 4096 + 32);
    }
#pragma unroll
    for (int nt = 0; nt < 4; ++nt) {
      short8 b0 = *(const short8*)&bs[(nt * 16 + n16) * 64 + ((quad ^ (n16 & 7)) * 8)];
      short8 b1 = *(const short8*)&bs[(nt * 16 + n16) * 64 + (((quad + 4) ^ (n16 & 7)) * 8)];
      acc[nt] = __builtin_amdgcn_mfma_f32_16x16x32_bf16(a0, b0, acc[nt], 0, 0, 0);
      acc[nt] = __builtin_amdgcn_mfma_f32_16x16x32_bf16(a1, b1, acc[nt], 0, 0, 0);
    }
  }
#pragma unroll
  for (int nt = 0; nt < 4; ++nt)
#pragma unroll
    for (int reg = 0; reg < 4; ++reg)
      out[((size_t)b * 512 + ot * 64 + w * 16 + quad * 4 + reg) * LL + s0 + nt * 16 + n16] =
          acc[nt][reg];
}

// ---------------- MFMA flash attention, fixed-max softmax (R5, 64-row) ---
__global__ __launch_bounds__(256, 4) void attn_kernel(
    const unsigned short* __restrict__ qbf, const unsigned short* __restrict__ kbf,
    const unsigned short* __restrict__ vbf, const unsigned short* __restrict__ relTh,
    const unsigned short* __restrict__ relTw, unsigned short* __restrict__ abf) {
  __shared__ __align__(16) char smem[28672];
  unsigned short* ks = (unsigned short*)smem;             // [64][64] swizzled
  unsigned short* vs = (unsigned short*)(smem + 8192);    // [32][64] swizzled
  unsigned short* ps = (unsigned short*)(smem + 12288);   // 4x[16][64]; rht transient
  unsigned short* rwtT = (unsigned short*)(smem + 20480); // [64 m][64 row] swizzled
  float* obuf = (float*)smem;                             // [64][33] fp32 overlay

  const int tid = threadIdx.x;
  const int lane = tid & 63, w = tid >> 6;
  const int n16 = lane & 15, quad = lane >> 4;
  const int blk = blockIdx.x;
  const int bn = blk & 63, qb = blk >> 6;
  const int n = bn & 7, b = bn >> 3;
  const int s0 = qb * 64;
  const int aa = 2 * qb + (w >> 1);
  const int pb = (w & 1) * 16;

  const unsigned short* qbase = qbf + ((size_t)(b * 8 + n)) * LL * 64;
  const unsigned short* kbase = kbf + ((size_t)(b * 8 + n)) * LL * 64;
  const unsigned short* vbase = vbf + ((size_t)(b * 8 + n)) * 32 * LL;

  const int ck = tid & 7;
  const int trow = tid >> 3;

  uint4 pk0 = *(const uint4*)(kbase + trow * 64 + ck * 8);
  uint4 pk1 = *(const uint4*)(kbase + (trow + 32) * 64 + ck * 8);
  uint4 pv = *(const uint4*)(vbase + (size_t)trow * LL + ck * 8);

  {
    const int sT = (pb + n16) * 32 + aa;
    short8 ra0 = *(const short8*)(qbase + (size_t)sT * 64 + quad * 8);
    short8 ra1 = *(const short8*)(qbase + (size_t)sT * 64 + 32 + quad * 8);
#pragma unroll
    for (int tbl = 0; tbl < 2; ++tbl) {
      const unsigned short* rel = tbl ? relTh : relTw;
      f32x4 acc[4];
#pragma unroll
      for (int mt = 0; mt < 4; ++mt) acc[mt] = (f32x4){0.f, 0.f, 0.f, 0.f};
#pragma unroll
      for (int mt = 0; mt < 4; ++mt) {
        short8 b0 = *(const short8*)(rel + (mt * 16 + n16) * 64 + quad * 8);
        short8 b1 = *(const short8*)(rel + (mt * 16 + n16) * 64 + 32 + quad * 8);
        acc[mt] = __builtin_amdgcn_mfma_f32_16x16x32_bf16(ra0, b0, acc[mt], 0, 0, 0);
        acc[mt] = __builtin_amdgcn_mfma_f32_16x16x32_bf16(ra1, b1, acc[mt], 0, 0, 0);
      }
      if (tbl == 0) {
#pragma unroll
        for (int mt = 0; mt < 4; ++mt)
#pragma unroll
          for (int reg = 0; reg < 4; ++reg)
            rwtT[(mt * 16 + n16) * 64 +
                 ((w * 16 + quad * 4 + reg) ^ ((n16 & 7) * 8))] = f2bf(acc[mt][reg]);
      } else {
#pragma unroll
        for (int mt = 0; mt < 4; ++mt)
#pragma unroll
          for (int reg = 0; reg < 4; ++reg)
            ps[(w * 16 + quad * 4 + reg) * 64 + mt * 16 + n16] = f2bf(acc[mt][reg]);
      }
    }
  }
  short8 qf0 = *(const short8*)(qbase + (size_t)(s0 + w * 16 + n16) * 64 + quad * 8);
  short8 qf1 = *(const short8*)(qbase + (size_t)(s0 + w * 16 + n16) * 64 + 32 + quad * 8);
  __syncthreads();
  float rhreg[2][4];
#pragma unroll
  for (int tt1 = 0; tt1 < 2; ++tt1)
#pragma unroll
    for (int reg = 0; reg < 4; ++reg) {
      const int iL = quad * 4 + reg;
      rhreg[tt1][reg] = bf2f(ps[(w * 16 + iL) * 64 + tt1 * 16 + n16 + 31 - pb - iL]);
    }

  float lacc[4] = {0.f, 0.f, 0.f, 0.f};
  f32x4 oacc[2];
  oacc[0] = (f32x4){0.f, 0.f, 0.f, 0.f};
  oacc[1] = (f32x4){0.f, 0.f, 0.f, 0.f};

  unsigned short* psw = ps + w * 1024;
  const int rb = w * 16 + quad * 4;

  for (int kt64 = 0; kt64 < 16; ++kt64) {
    const int t0 = kt64 * 64;
    __syncthreads();
    *(uint4*)&ks[trow * 64 + ((ck ^ (trow & 7)) * 8)] = pk0;
    *(uint4*)&ks[(trow + 32) * 64 + ((ck ^ (trow & 7)) * 8)] = pk1;
    *(uint4*)&vs[trow * 64 + ((ck ^ (trow & 7)) * 8)] = pv;
    __syncthreads();
    if (kt64 < 15) {
      const unsigned short* kg = kbase + (size_t)(t0 + 64) * 64;
      pk0 = *(const uint4*)(kg + trow * 64 + ck * 8);
      pk1 = *(const uint4*)(kg + (trow + 32) * 64 + ck * 8);
      pv = *(const uint4*)(vbase + (size_t)trow * LL + t0 + 64 + ck * 8);
    }

    f32x4 sacc[4];
#pragma unroll
    for (int tt = 0; tt < 4; ++tt) sacc[tt] = (f32x4){0.f, 0.f, 0.f, 0.f};
#pragma unroll
    for (int tt = 0; tt < 4; ++tt) {
      short8 kb0 = *(const short8*)&ks[(tt * 16 + n16) * 64 + ((quad ^ (n16 & 7)) * 8)];
      short8 kb1 = *(const short8*)&ks[(tt * 16 + n16) * 64 + (((quad + 4) ^ (n16 & 7)) * 8)];
      sacc[tt] = __builtin_amdgcn_mfma_f32_16x16x32_bf16(qf0, kb0, sacc[tt], 0, 0, 0);
      sacc[tt] = __builtin_amdgcn_mfma_f32_16x16x32_bf16(qf1, kb1, sacc[tt], 0, 0, 0);
    }
    float rwv[2][4];
#pragma unroll
    for (int h = 0; h < 2; ++h) {
      const int mw = (t0 >> 5) + h - aa + 31;
      const ushort4 rw4 = *(const ushort4*)&rwtT[mw * 64 + (rb ^ ((mw & 7) * 8))];
      rwv[h][0] = bf2f(rw4.x); rwv[h][1] = bf2f(rw4.y);
      rwv[h][2] = bf2f(rw4.z); rwv[h][3] = bf2f(rw4.w);
    }
#pragma unroll
    for (int tt = 0; tt < 4; ++tt)
#pragma unroll
      for (int reg = 0; reg < 4; ++reg) {
        const float e =
            __builtin_amdgcn_exp2f(sacc[tt][reg] + rwv[tt >> 1][reg] + rhreg[tt & 1][reg]);
        lacc[reg] += e;
        const int r = quad * 4 + reg;
        psw[r * 64 + (((tt * 2 + (n16 >> 3)) ^ (r & 7)) * 8) + (n16 & 7)] =
            (unsigned short)(__float_as_uint(e) >> 16);
      }
    __asm__ volatile("s_waitcnt lgkmcnt(0)" ::: "memory");
#pragma unroll
    for (int kt = 0; kt < 2; ++kt) {
      short8 pa = *(const short8*)&psw[n16 * 64 + (((quad + 4 * kt) ^ (n16 & 7)) * 8)];
#pragma unroll
      for (int ct = 0; ct < 2; ++ct) {
        short8 vb = *(const short8*)&vs[(ct * 16 + n16) * 64 + (((quad + 4 * kt) ^ (n16 & 7)) * 8)];
        oacc[ct] = __builtin_amdgcn_mfma_f32_16x16x32_bf16(pa, vb, oacc[ct], 0, 0, 0);
      }
    }
  }
  float linv[4];
#pragma unroll
  for (int reg = 0; reg < 4; ++reg) {
    float l = lacc[reg];
#pragma unroll
    for (int m = 1; m < 16; m <<= 1) l += __shfl_xor(l, m, 16);
    linv[reg] = 1.0f / l;
  }
  __syncthreads();
#pragma unroll
  for (int ct = 0; ct < 2; ++ct)
#pragma unroll
    for (int reg = 0; reg < 4; ++reg)
      obuf[(w * 16 + quad * 4 + reg) * 33 + ct * 16 + n16] = oacc[ct][reg] * linv[reg];
  __syncthreads();
  {
    const int row = tid >> 2;
    const int cseg = (tid & 3) * 8;
    unsigned short buf8[8];
#pragma unroll
    for (int m = 0; m < 8; ++m) buf8[m] = f2bf(obuf[row * 33 + cseg + m]);
    *(uint4*)(abf + (((size_t)b * LL) + s0 + row) * 256 + n * 32 + cseg) = *(uint4*)&buf8[0];
  }
}

// ------- output projection: A-frags direct from global, B in LDS ---------
__global__ __launch_bounds__(256) void proj_mfma(
    const unsigned short* __restrict__ abf, const unsigned short* __restrict__ woutbf,
    float* __restrict__ out) {
  __shared__ __align__(16) unsigned short bs[64 * 64];
  const int tid = threadIdx.x;
  const int lane = tid & 63, w = tid >> 6;
  const int n16 = lane & 15, quad = lane >> 4;
  const int ot = blockIdx.x;
  const int st = blockIdx.y;
  const int b = blockIdx.z;
  const int s0 = st * 64;
  const int trow = tid >> 3, ck = tid & 7;

  const unsigned short* ab = abf + ((size_t)b * LL + s0) * 256;
  const unsigned short* wA = woutbf + (size_t)ot * 16384 + (w * 16 + n16) * 64 + quad * 8;

  f32x4 acc[4];
#pragma unroll
  for (int nt = 0; nt < 4; ++nt) acc[nt] = (f32x4){0.f, 0.f, 0.f, 0.f};

  uint4 rb0 = *(const uint4*)(ab + (size_t)trow * 256 + ck * 8);
  uint4 rb1 = *(const uint4*)(ab + (size_t)(trow + 32) * 256 + ck * 8);
  short8 af0 = *(const short8*)(wA);
  short8 af1 = *(const short8*)(wA + 32);
#pragma unroll
  for (int kc = 0; kc < 4; ++kc) {
    __syncthreads();
    *(uint4*)&bs[trow * 64 + ((ck ^ (trow & 7)) * 8)] = rb0;
    *(uint4*)&bs[(trow + 32) * 64 + ((ck ^ (trow & 7)) * 8)] = rb1;
    __syncthreads();
    short8 a0 = af0, a1 = af1;
    if (kc < 3) {
      const int c0 = (kc + 1) * 64;
      rb0 = *(const uint4*)(ab + (size_t)trow * 256 + c0 + ck * 8);
      rb1 = *(const uint4*)(ab + (size_t)(trow + 32) * 256 + c0 + ck * 8);
      af0 = *(const short8*)(wA + (kc + 1) * 4096);
      af1 = *(const short8*)(wA + (kc + 1) * 4096 + 32);
    }
#pragma unroll
    for (int nt = 0; nt < 4; ++nt) {
      short8 b0 = *(const short8*)&bs[(nt * 16 + n16) * 64 + ((quad ^ (n16 & 7)) * 8)];
      short8 b1 = *(const short8*)&bs[(nt * 16 + n16) * 64 + (((quad + 4) ^ (n16 & 7)) * 8)];
      acc[nt] = __builtin_amdgcn_mfma_f32_16x16x32_bf16(a0, b0, acc[nt], 0, 0, 0);
      acc[nt] = __builtin_amdgcn_mfma_f32_16x16x32_bf16(a1, b1, acc[nt], 0, 0, 0);
    }
  }
#pragma unroll
  for (int nt = 0; nt < 4; ++nt)
#pragma unroll
    for (int reg = 0; reg < 4; ++reg)
      out[((size_t)b * 512 + 256 + ot * 64 + w * 16 + quad * 4 + reg) * LL + s0 + nt * 16 + n16] =
          acc[nt][reg];
}

extern "C" void kernel_launch(void* const* d_in, const int* in_sizes, int n_in,
                              void* d_out, int out_size, void* d_ws, size_t ws_size,
                              hipStream_t stream) {
  const float* x     = (const float*)d_in[0];
  const float* wqkv  = (const float*)d_in[1];
  const float* wconv = (const float*)d_in[2];
  const float* wout  = (const float*)d_in[3];
  const float* krh   = (const float*)d_in[4];
  const float* krw   = (const float*)d_in[5];
  float* out = (float*)d_out;

  unsigned short* qbf = (unsigned short*)d_ws;
  unsigned short* kbf = qbf + (size_t)NB * 8 * LL * 64;
  unsigned short* vbf = kbf + (size_t)NB * 8 * LL * 64;
  unsigned short* abf = vbf + (size_t)NB * DVC * LL;
  unsigned short* relTh = abf + (size_t)NB * LL * DVC;
  unsigned short* relTw = relTh + 4096;
  unsigned short* xTp = relTw + 4096;
  unsigned short* wtap = xTp + (size_t)NB * XPSTRIDE;
  unsigned short* wqbf = wtap + 589824;
  unsigned short* woutbf = wqbf + 327680;

  prep_weights<<<dim3(4928), 256, 0, stream>>>(wconv, wqkv, wout, krh, krw,
                                               wtap, wqbf, woutbf, relTh, relTw, xTp);
  xpad_interior<<<dim3(16, 8), 256, 0, stream>>>(x, xTp);
  qkv_mfma<<<dim3(20, 16, NB), 256, 0, stream>>>(xTp, wqbf, qbf, kbf, vbf);
  conv_mfma<<<dim3(4, 16, NB), 256, 0, stream>>>(xTp, wtap, out);
  attn_kernel<<<dim3(1024), 256, 0, stream>>>(qbf, kbf, vbf, relTh, relTw, abf);
  proj_mfma<<<dim3(4, 16, NB), 256, 0, stream>>>(abf, woutbf, out);
}

// Round 9
// 161.018 us; speedup vs baseline: 1.1187x; 1.0106x over previous
//
#include <hip/hip_runtime.h>
#include <cstddef>
#include <cstdint>

#define NB 8
#define CIN 256
#define LL 1024
#define DKC 512
#define DVC 256
#define XPSTRIDE 295936  // 34*34*256

typedef short short8 __attribute__((ext_vector_type(8)));
typedef float f32x4 __attribute__((ext_vector_type(4)));

__device__ __forceinline__ unsigned short f2bf(float f) {
  unsigned int u = __float_as_uint(f);
  u += 0x7fffu + ((u >> 16) & 1u);
  return (unsigned short)(u >> 16);
}
__device__ __forceinline__ float bf2f(unsigned short u) {
  return __uint_as_float(((unsigned int)u) << 16);
}

// ------- fused prep: xpad tiles (blocks 0..127) + weight/rel/border ------
// Weights emitted in A-FRAGMENT order [tile][kchunk][row 64][k 64].
// q rows carry 1/8 (dkh^-0.5) AND log2(e) so attention can use exp2.
__global__ __launch_bounds__(256) void prep_all(
    const float* __restrict__ x, const float* __restrict__ wconv,
    const float* __restrict__ wqkv, const float* __restrict__ wout,
    const float* __restrict__ krh, const float* __restrict__ krw,
    unsigned short* __restrict__ wtap, unsigned short* __restrict__ wqbf,
    unsigned short* __restrict__ woutbf, unsigned short* __restrict__ relTh,
    unsigned short* __restrict__ relTw, unsigned short* __restrict__ xTp) {
  __shared__ float tile[64][65];
  const int tid = threadIdx.x;
  if (blockIdx.x < 128) {
    // ---- xpad interior: x[b,:,s0..s0+64) -> xTp[b][h+1][w+1][c] bf16 ----
    const int st = blockIdx.x & 15;
    const int b = blockIdx.x >> 4;
    const int s0 = st * 64;
    const int h0 = st * 2;
    for (int cc = 0; cc < 4; ++cc) {
      const int c0 = cc * 64;
      {
        const int row = tid >> 2;
        const int j0 = (tid & 3) * 16;
#pragma unroll
        for (int k = 0; k < 4; ++k)
          *(float4*)&tile[row][j0 + k * 4] =
              *(const float4*)(x + ((size_t)(b * CIN + c0 + row)) * LL + s0 + j0 + k * 4);
      }
      __syncthreads();
      {
        const int sl = tid >> 2;
        const int cb = (tid & 3) * 16;
        unsigned short buf[16];
#pragma unroll
        for (int m = 0; m < 16; ++m) buf[m] = f2bf(tile[cb + m][sl]);
        const int hp = h0 + (sl >> 5) + 1;
        const int wp = (sl & 31) + 1;
        unsigned short* dst = xTp + (size_t)b * XPSTRIDE + (hp * 34 + wp) * 256 + c0 + cb;
        *(uint4*)dst = *(uint4*)&buf[0];
        *(uint4*)(dst + 8) = *(uint4*)&buf[8];
      }
      __syncthreads();
    }
    return;
  }
  const int idx = (blockIdx.x - 128) * 256 + tid;
  if (idx < 589824) {
    // wtap layout: [ot 4][tap 9][kc 4][row 64][kin 64]
    const int g = idx >> 14;           // ot*9+tap
    const int ot = g / 9, tap = g - ot * 9;
    const int rem2 = idx & 16383;
    const int kc = rem2 >> 12;
    const int row = (rem2 >> 6) & 63, kin = rem2 & 63;
    const int o = ot * 64 + row, c = kc * 64 + kin;
    wtap[idx] = f2bf(wconv[(size_t)(o * 256 + c) * 9 + tap]);
  } else if (idx < 917504) {
    // wqbf layout: [ot 20][kc 4][row 64][kin 64]
    const int j = idx - 589824;
    const int g = j >> 12;             // ot*4+kc
    const int ot = g >> 2, kc = g & 3;
    const int row = (j >> 6) & 63, kin = j & 63;
    const int o = ot * 64 + row, c = kc * 64 + kin;
    const float sc = (o < DKC) ? 0.125f * 1.44269504088896f : 1.0f;
    wqbf[j] = f2bf(wqkv[o * 256 + c] * sc);
  } else if (idx < 983040) {
    // woutbf layout: [ot 4][kc 4][row 64][kin 64]
    const int j = idx - 917504;
    const int g = j >> 12;
    const int o = (g >> 2) * 64 + ((j >> 6) & 63);
    const int c = (g & 3) * 64 + (j & 63);
    woutbf[j] = f2bf(wout[o * 256 + c]);
  } else if (idx < 991232) {
    const int j = idx - 983040;
    const int tbl = j >> 12;
    const int rest = j & 4095;
    const int m = rest >> 6, c = rest & 63;
    const float* src = tbl ? krw : krh;
    unsigned short* dst = tbl ? relTw : relTh;
    const float v = (m < 63) ? src[c * 63 + m] : 0.f;
    dst[m * 64 + c] = f2bf(v);
  } else {
    const int j2 = idx - 991232;  // border zero: 8*132*256
    const int b = j2 / 33792;
    const int rem = j2 - b * 33792;
    const int pos = rem >> 8, c = rem & 255;
    int hp, wp;
    if (pos < 34) { hp = 0; wp = pos; }
    else if (pos < 68) { hp = 33; wp = pos - 34; }
    else if (pos < 100) { hp = pos - 68 + 1; wp = 0; }
    else { hp = pos - 100 + 1; wp = 33; }
    xTp[(size_t)b * XPSTRIDE + (hp * 34 + wp) * 256 + c] = 0;
  }
}

// ------- QKV projection: A-frags direct from global, B staged in LDS -----
__global__ __launch_bounds__(256) void qkv_mfma(
    const unsigned short* __restrict__ xTp, const unsigned short* __restrict__ wqbf,
    unsigned short* __restrict__ qbf, unsigned short* __restrict__ kbf,
    unsigned short* __restrict__ vbf) {
  __shared__ __align__(16) char qsmem[16640];  // bs (8KB) then trans overlay
  unsigned short* bs = (unsigned short*)qsmem;
  float (*trans)[65] = (float(*)[65])qsmem;
  const int tid = threadIdx.x;
  const int lane = tid & 63, w = tid >> 6;
  const int n16 = lane & 15, quad = lane >> 4;
  const int ot = blockIdx.x;   // 0..19
  const int st = blockIdx.y;   // 0..15
  const int b = blockIdx.z;
  const int s0 = st * 64;
  const int h0 = st * 2;
  const int trow = tid >> 3, ck = tid & 7;

  const unsigned short* xb = xTp + (size_t)b * XPSTRIDE;
  const unsigned short* wA = wqbf + (size_t)ot * 16384 + (w * 16 + n16) * 64 + quad * 8;
  const int wpos = (trow & 31) + 1;

  f32x4 acc[4];
#pragma unroll
  for (int nt = 0; nt < 4; ++nt) acc[nt] = (f32x4){0.f, 0.f, 0.f, 0.f};

  uint4 rb0 = *(const uint4*)(xb + (size_t)((h0 + 1) * 34 + wpos) * 256 + ck * 8);
  uint4 rb1 = *(const uint4*)(xb + (size_t)((h0 + 2) * 34 + wpos) * 256 + ck * 8);
  short8 af0 = *(const short8*)(wA);
  short8 af1 = *(const short8*)(wA + 32);
#pragma unroll
  for (int kc = 0; kc < 4; ++kc) {
    __syncthreads();
    *(uint4*)&bs[trow * 64 + ((ck ^ (trow & 7)) * 8)] = rb0;
    *(uint4*)&bs[(trow + 32) * 64 + ((ck ^ (trow & 7)) * 8)] = rb1;
    __syncthreads();
    short8 a0 = af0, a1 = af1;
    if (kc < 3) {
      const int c0 = (kc + 1) * 64;
      rb0 = *(const uint4*)(xb + (size_t)((h0 + 1) * 34 + wpos) * 256 + c0 + ck * 8);
      rb1 = *(const uint4*)(xb + (size_t)((h0 + 2) * 34 + wpos) * 256 + c0 + ck * 8);
      af0 = *(const short8*)(wA + (kc + 1) * 4096);
      af1 = *(const short8*)(wA + (kc + 1) * 4096 + 32);
    }
#pragma unroll
    for (int nt = 0; nt < 4; ++nt) {
      short8 b0 = *(const short8*)&bs[(nt * 16 + n16) * 64 + ((quad ^ (n16 & 7)) * 8)];
      short8 b1 = *(const short8*)&bs[(nt * 16 + n16) * 64 + (((quad + 4) ^ (n16 & 7)) * 8)];
      acc[nt] = __builtin_amdgcn_mfma_f32_16x16x32_bf16(a0, b0, acc[nt], 0, 0, 0);
      acc[nt] = __builtin_amdgcn_mfma_f32_16x16x32_bf16(a1, b1, acc[nt], 0, 0, 0);
    }
  }
  __syncthreads();
#pragma unroll
  for (int nt = 0; nt < 4; ++nt)
#pragma unroll
    for (int reg = 0; reg < 4; ++reg)
      trans[w * 16 + quad * 4 + reg][nt * 16 + n16] = acc[nt][reg];
  __syncthreads();
  const int sl = tid >> 2;
  const int cseg = (tid & 3) * 16;
  unsigned short buf[16];
  if (ot < 16) {
#pragma unroll
    for (int m = 0; m < 16; ++m) buf[m] = f2bf(trans[cseg + m][sl]);
    unsigned short* dst;
    int head;
    if (ot < 8) { dst = qbf; head = ot; }
    else { dst = kbf; head = ot - 8; }
    const size_t base = (((size_t)(b * 8 + head)) * LL + s0 + sl) * 64 + cseg;
    *(uint4*)(dst + base) = *(uint4*)&buf[0];
    *(uint4*)(dst + base + 8) = *(uint4*)&buf[8];
  } else {
#pragma unroll
    for (int m = 0; m < 16; ++m) buf[m] = f2bf(trans[sl][cseg + m]);
    unsigned short* dst = vbf + ((size_t)b * DVC + (ot - 16) * 64 + sl) * LL + s0 + cseg;
    *(uint4*)dst = *(uint4*)&buf[0];
    *(uint4*)(dst + 8) = *(uint4*)&buf[8];
  }
}

// ------- conv implicit GEMM: A-frags direct from global, B in LDS --------
__global__ __launch_bounds__(256) void conv_mfma(
    const unsigned short* __restrict__ xTp, const unsigned short* __restrict__ wtap,
    float* __restrict__ out) {
  __shared__ __align__(16) unsigned short bs[64 * 64];
  const int tid = threadIdx.x;
  const int lane = tid & 63, w = tid >> 6;
  const int n16 = lane & 15, quad = lane >> 4;
  const int ot = blockIdx.x;
  const int st = blockIdx.y;
  const int b = blockIdx.z;
  const int s0 = st * 64;
  const int h0 = st * 2;
  const int trow = tid >> 3;
  const int ck = tid & 7;

  const unsigned short* xb = xTp + (size_t)b * XPSTRIDE;
  const unsigned short* wA = wtap + (size_t)ot * 147456 + (w * 16 + n16) * 64 + quad * 8;

  f32x4 acc[4];
#pragma unroll
  for (int nt = 0; nt < 4; ++nt) acc[nt] = (f32x4){0.f, 0.f, 0.f, 0.f};

  uint4 rb0, rb1;
  auto loadB = [&](int it) {
    const int tap = it >> 2;
    const int c0 = (it & 3) * 64;
    const int dh = tap / 3 - 1;
    const int dw = tap - (tap / 3) * 3 - 1;
    const int wp = (trow & 31) + dw + 1;
    rb0 = *(const uint4*)(xb + (size_t)((h0 + dh + 1) * 34 + wp) * 256 + c0 + ck * 8);
    rb1 = *(const uint4*)(xb + (size_t)((h0 + dh + 2) * 34 + wp) * 256 + c0 + ck * 8);
  };
  loadB(0);
  short8 af0 = *(const short8*)(wA);
  short8 af1 = *(const short8*)(wA + 32);
  for (int it = 0; it < 36; ++it) {
    __syncthreads();
    *(uint4*)&bs[trow * 64 + ((ck ^ (trow & 7)) * 8)] = rb0;
    *(uint4*)&bs[(trow + 32) * 64 + ((ck ^ (trow & 7)) * 8)] = rb1;
    __syncthreads();
    short8 a0 = af0, a1 = af1;
    if (it < 35) {
      loadB(it + 1);
      af0 = *(const short8*)(wA + (size_t)(it + 1) * 4096);
      af1 = *(const short8*)(wA + (size_t)(it + 1) * 4096 + 32);
    }
#pragma unroll
    for (int nt = 0; nt < 4; ++nt) {
      short8 b0 = *(const short8*)&bs[(nt * 16 + n16) * 64 + ((quad ^ (n16 & 7)) * 8)];
      short8 b1 = *(const short8*)&bs[(nt * 16 + n16) * 64 + (((quad + 4) ^ (n16 & 7)) * 8)];
      acc[nt] = __builtin_amdgcn_mfma_f32_16x16x32_bf16(a0, b0, acc[nt], 0, 0, 0);
      acc[nt] = __builtin_amdgcn_mfma_f32_16x16x32_bf16(a1, b1, acc[nt], 0, 0, 0);
    }
  }
#pragma unroll
  for (int nt = 0; nt < 4; ++nt)
#pragma unroll
    for (int reg = 0; reg < 4; ++reg)
      out[((size_t)b * 512 + ot * 64 + w * 16 + quad * 4 + reg) * LL + s0 + nt * 16 + n16] =
          acc[nt][reg];
}

// ------- MFMA flash attention, 128 q-rows/block, fixed-max softmax -------
// grid 512: bn = blk&63 (head/batch -> XCD locality), qt = blk>>6 (8 tiles).
__global__ __launch_bounds__(256, 2) void attn_kernel(
    const unsigned short* __restrict__ qbf, const unsigned short* __restrict__ kbf,
    const unsigned short* __restrict__ vbf, const unsigned short* __restrict__ relTh,
    const unsigned short* __restrict__ relTw, unsigned short* __restrict__ abf) {
  __shared__ __align__(16) char smem[45056];
  unsigned short* ks = (unsigned short*)smem;             // [64 key][64 c] swizzled
  unsigned short* vs = (unsigned short*)(smem + 8192);    // [32 cv][64 key] swizzled
  unsigned short* ps = (unsigned short*)(smem + 12288);   // [128 q][64 key]; rh transient
  unsigned short* rwtT = (unsigned short*)(smem + 28672); // [64 m][128 row] swizzled
  float* obuf = (float*)smem;                             // [128][33] fp32 overlay

  const int tid = threadIdx.x;
  const int lane = tid & 63, w = tid >> 6;
  const int n16 = lane & 15, quad = lane >> 4;
  const int blk = blockIdx.x;
  const int bn = blk & 63, qt = blk >> 6;
  const int n = bn & 7, b = bn >> 3;
  const int s0 = qt * 128;
  const int pb = (w & 1) * 16;
  const int aar[2] = {4 * qt + (w >> 1), 4 * qt + 2 + (w >> 1)};

  const unsigned short* qbase = qbf + ((size_t)(b * 8 + n)) * LL * 64;
  const unsigned short* kbase = kbf + ((size_t)(b * 8 + n)) * LL * 64;
  const unsigned short* vbase = vbf + ((size_t)(b * 8 + n)) * 32 * LL;

  const int ck = tid & 7;
  const int trow = tid >> 3;

  uint4 pk0 = *(const uint4*)(kbase + trow * 64 + ck * 8);
  uint4 pk1 = *(const uint4*)(kbase + (trow + 32) * 64 + ck * 8);
  uint4 pv = *(const uint4*)(vbase + (size_t)trow * LL + ck * 8);

#pragma unroll
  for (int rs = 0; rs < 2; ++rs) {
    const int aa = aar[rs];
    const int sT = (pb + n16) * 32 + aa;
    short8 ra0 = *(const short8*)(qbase + (size_t)sT * 64 + quad * 8);
    short8 ra1 = *(const short8*)(qbase + (size_t)sT * 64 + 32 + quad * 8);
#pragma unroll
    for (int tbl = 0; tbl < 2; ++tbl) {
      const unsigned short* rel = tbl ? relTh : relTw;
      f32x4 acc[4];
#pragma unroll
      for (int mt = 0; mt < 4; ++mt) acc[mt] = (f32x4){0.f, 0.f, 0.f, 0.f};
#pragma unroll
      for (int mt = 0; mt < 4; ++mt) {
        short8 b0 = *(const short8*)(rel + (mt * 16 + n16) * 64 + quad * 8);
        short8 b1 = *(const short8*)(rel + (mt * 16 + n16) * 64 + 32 + quad * 8);
        acc[mt] = __builtin_amdgcn_mfma_f32_16x16x32_bf16(ra0, b0, acc[mt], 0, 0, 0);
        acc[mt] = __builtin_amdgcn_mfma_f32_16x16x32_bf16(ra1, b1, acc[mt], 0, 0, 0);
      }
      if (tbl == 0) {
#pragma unroll
        for (int mt = 0; mt < 4; ++mt)
#pragma unroll
          for (int reg = 0; reg < 4; ++reg)
            rwtT[(mt * 16 + n16) * 128 +
                 ((rs * 64 + w * 16 + quad * 4 + reg) ^ ((n16 & 7) * 8))] = f2bf(acc[mt][reg]);
      } else {
#pragma unroll
        for (int mt = 0; mt < 4; ++mt)
#pragma unroll
          for (int reg = 0; reg < 4; ++reg)
            ps[(rs * 64 + w * 16 + quad * 4 + reg) * 64 + mt * 16 + n16] = f2bf(acc[mt][reg]);
      }
    }
  }
  short8 qf[2][2];
#pragma unroll
  for (int rs = 0; rs < 2; ++rs) {
    const size_t qrow = (size_t)(s0 + rs * 64 + w * 16 + n16) * 64;
    qf[rs][0] = *(const short8*)(qbase + qrow + quad * 8);
    qf[rs][1] = *(const short8*)(qbase + qrow + 32 + quad * 8);
  }
  __syncthreads();
  float rhreg[2][2][4];
#pragma unroll
  for (int rs = 0; rs < 2; ++rs)
#pragma unroll
    for (int tt1 = 0; tt1 < 2; ++tt1)
#pragma unroll
      for (int reg = 0; reg < 4; ++reg) {
        const int iL = quad * 4 + reg;
        rhreg[rs][tt1][reg] =
            bf2f(ps[(rs * 64 + w * 16 + iL) * 64 + tt1 * 16 + n16 + 31 - pb - iL]);
      }

  float lacc[2][4] = {};
  f32x4 oacc[2][2];
#pragma unroll
  for (int rs = 0; rs < 2; ++rs)
#pragma unroll
    for (int ct = 0; ct < 2; ++ct) oacc[rs][ct] = (f32x4){0.f, 0.f, 0.f, 0.f};

  const int rbq = w * 16 + quad * 4;

  for (int kt64 = 0; kt64 < 16; ++kt64) {
    const int t0 = kt64 * 64;
    __syncthreads();
    *(uint4*)&ks[trow * 64 + ((ck ^ (trow & 7)) * 8)] = pk0;
    *(uint4*)&ks[(trow + 32) * 64 + ((ck ^ (trow & 7)) * 8)] = pk1;
    *(uint4*)&vs[trow * 64 + ((ck ^ (trow & 7)) * 8)] = pv;
    __syncthreads();
    if (kt64 < 15) {
      const unsigned short* kg = kbase + (size_t)(t0 + 64) * 64;
      pk0 = *(const uint4*)(kg + trow * 64 + ck * 8);
      pk1 = *(const uint4*)(kg + (trow + 32) * 64 + ck * 8);
      pv = *(const uint4*)(vbase + (size_t)trow * LL + t0 + 64 + ck * 8);
    }

    f32x4 sacc[2][4];
#pragma unroll
    for (int rs = 0; rs < 2; ++rs)
#pragma unroll
      for (int tt = 0; tt < 4; ++tt) sacc[rs][tt] = (f32x4){0.f, 0.f, 0.f, 0.f};
#pragma unroll
    for (int tt = 0; tt < 4; ++tt) {
      short8 kb0 = *(const short8*)&ks[(tt * 16 + n16) * 64 + ((quad ^ (n16 & 7)) * 8)];
      short8 kb1 = *(const short8*)&ks[(tt * 16 + n16) * 64 + (((quad + 4) ^ (n16 & 7)) * 8)];
#pragma unroll
      for (int rs = 0; rs < 2; ++rs) {
        sacc[rs][tt] = __builtin_amdgcn_mfma_f32_16x16x32_bf16(qf[rs][0], kb0, sacc[rs][tt], 0, 0, 0);
        sacc[rs][tt] = __builtin_amdgcn_mfma_f32_16x16x32_bf16(qf[rs][1], kb1, sacc[rs][tt], 0, 0, 0);
      }
    }
    float rwv[2][2][4];
#pragma unroll
    for (int rs = 0; rs < 2; ++rs)
#pragma unroll
      for (int h = 0; h < 2; ++h) {
        const int mw = (t0 >> 5) + h - aar[rs] + 31;
        const ushort4 rw4 =
            *(const ushort4*)&rwtT[mw * 128 + ((rs * 64 + rbq) ^ ((mw & 7) * 8))];
        rwv[rs][h][0] = bf2f(rw4.x); rwv[rs][h][1] = bf2f(rw4.y);
        rwv[rs][h][2] = bf2f(rw4.z); rwv[rs][h][3] = bf2f(rw4.w);
      }
#pragma unroll
    for (int rs = 0; rs < 2; ++rs)
#pragma unroll
      for (int tt = 0; tt < 4; ++tt)
#pragma unroll
        for (int reg = 0; reg < 4; ++reg) {
          const float e = __builtin_amdgcn_exp2f(sacc[rs][tt][reg] + rwv[rs][tt >> 1][reg] +
                                                 rhreg[rs][tt & 1][reg]);
          lacc[rs][reg] += e;
          const int r = quad * 4 + reg;
          ps[(rs * 64 + w * 16 + r) * 64 + (((tt * 2 + (n16 >> 3)) ^ (r & 7)) * 8) + (n16 & 7)] =
              (unsigned short)(__float_as_uint(e) >> 16);
        }
    __asm__ volatile("s_waitcnt lgkmcnt(0)" ::: "memory");
#pragma unroll
    for (int kt = 0; kt < 2; ++kt) {
      short8 pa[2];
#pragma unroll
      for (int rs = 0; rs < 2; ++rs)
        pa[rs] = *(const short8*)&ps[(rs * 64 + w * 16 + n16) * 64 +
                                     (((quad + 4 * kt) ^ (n16 & 7)) * 8)];
#pragma unroll
      for (int ct = 0; ct < 2; ++ct) {
        short8 vb = *(const short8*)&vs[(ct * 16 + n16) * 64 + (((quad + 4 * kt) ^ (n16 & 7)) * 8)];
#pragma unroll
        for (int rs = 0; rs < 2; ++rs)
          oacc[rs][ct] = __builtin_amdgcn_mfma_f32_16x16x32_bf16(pa[rs], vb, oacc[rs][ct], 0, 0, 0);
      }
    }
  }
  float linv[2][4];
#pragma unroll
  for (int rs = 0; rs < 2; ++rs)
#pragma unroll
    for (int reg = 0; reg < 4; ++reg) {
      float l = lacc[rs][reg];
#pragma unroll
      for (int m = 1; m < 16; m <<= 1) l += __shfl_xor(l, m, 16);
      linv[rs][reg] = 1.0f / l;
    }
  __syncthreads();
#pragma unroll
  for (int rs = 0; rs < 2; ++rs)
#pragma unroll
    for (int ct = 0; ct < 2; ++ct)
#pragma unroll
      for (int reg = 0; reg < 4; ++reg)
        obuf[(rs * 64 + w * 16 + quad * 4 + reg) * 33 + ct * 16 + n16] =
            oacc[rs][ct][reg] * linv[rs][reg];
  __syncthreads();
  {
    const int row = tid >> 1;            // 0..127
    const int cseg = (tid & 1) * 16;     // cv chunk
    unsigned short buf16[16];
#pragma unroll
    for (int m = 0; m < 16; ++m) buf16[m] = f2bf(obuf[row * 33 + cseg + m]);
    unsigned short* dst = abf + (((size_t)b * LL) + s0 + row) * 256 + n * 32 + cseg;
    *(uint4*)dst = *(uint4*)&buf16[0];
    *(uint4*)(dst + 8) = *(uint4*)&buf16[8];
  }
}

// ------- output projection: A-frags direct from global, B in LDS ---------
__global__ __launch_bounds__(256) void proj_mfma(
    const unsigned short* __restrict__ abf, const unsigned short* __restrict__ woutbf,
    float* __restrict__ out) {
  __shared__ __align__(16) unsigned short bs[64 * 64];
  const int tid = threadIdx.x;
  const int lane = tid & 63, w = tid >> 6;
  const int n16 = lane & 15, quad = lane >> 4;
  const int ot = blockIdx.x;
  const int st = blockIdx.y;
  const int b = blockIdx.z;
  const int s0 = st * 64;
  const int trow = tid >> 3, ck = tid & 7;

  const unsigned short* ab = abf + ((size_t)b * LL + s0) * 256;
  const unsigned short* wA = woutbf + (size_t)ot * 16384 + (w * 16 + n16) * 64 + quad * 8;

  f32x4 acc[4];
#pragma unroll
  for (int nt = 0; nt < 4; ++nt) acc[nt] = (f32x4){0.f, 0.f, 0.f, 0.f};

  uint4 rb0 = *(const uint4*)(ab + (size_t)trow * 256 + ck * 8);
  uint4 rb1 = *(const uint4*)(ab + (size_t)(trow + 32) * 256 + ck * 8);
  short8 af0 = *(const short8*)(wA);
  short8 af1 = *(const short8*)(wA + 32);
#pragma unroll
  for (int kc = 0; kc < 4; ++kc) {
    __syncthreads();
    *(uint4*)&bs[trow * 64 + ((ck ^ (trow & 7)) * 8)] = rb0;
    *(uint4*)&bs[(trow + 32) * 64 + ((ck ^ (trow & 7)) * 8)] = rb1;
    __syncthreads();
    short8 a0 = af0, a1 = af1;
    if (kc < 3) {
      const int c0 = (kc + 1) * 64;
      rb0 = *(const uint4*)(ab + (size_t)trow * 256 + c0 + ck * 8);
      rb1 = *(const uint4*)(ab + (size_t)(trow + 32) * 256 + c0 + ck * 8);
      af0 = *(const short8*)(wA + (kc + 1) * 4096);
      af1 = *(const short8*)(wA + (kc + 1) * 4096 + 32);
    }
#pragma unroll
    for (int nt = 0; nt < 4; ++nt) {
      short8 b0 = *(const short8*)&bs[(nt * 16 + n16) * 64 + ((quad ^ (n16 & 7)) * 8)];
      short8 b1 = *(const short8*)&bs[(nt * 16 + n16) * 64 + (((quad + 4) ^ (n16 & 7)) * 8)];
      acc[nt] = __builtin_amdgcn_mfma_f32_16x16x32_bf16(a0, b0, acc[nt], 0, 0, 0);
      acc[nt] = __builtin_amdgcn_mfma_f32_16x16x32_bf16(a1, b1, acc[nt], 0, 0, 0);
    }
  }
#pragma unroll
  for (int nt = 0; nt < 4; ++nt)
#pragma unroll
    for (int reg = 0; reg < 4; ++reg)
      out[((size_t)b * 512 + 256 + ot * 64 + w * 16 + quad * 4 + reg) * LL + s0 + nt * 16 + n16] =
          acc[nt][reg];
}

extern "C" void kernel_launch(void* const* d_in, const int* in_sizes, int n_in,
                              void* d_out, int out_size, void* d_ws, size_t ws_size,
                              hipStream_t stream) {
  const float* x     = (const float*)d_in[0];
  const float* wqkv  = (const float*)d_in[1];
  const float* wconv = (const float*)d_in[2];
  const float* wout  = (const float*)d_in[3];
  const float* krh   = (const float*)d_in[4];
  const float* krw   = (const float*)d_in[5];
  float* out = (float*)d_out;

  unsigned short* qbf = (unsigned short*)d_ws;
  unsigned short* kbf = qbf + (size_t)NB * 8 * LL * 64;
  unsigned short* vbf = kbf + (size_t)NB * 8 * LL * 64;
  unsigned short* abf = vbf + (size_t)NB * DVC * LL;
  unsigned short* relTh = abf + (size_t)NB * LL * DVC;
  unsigned short* relTw = relTh + 4096;
  unsigned short* xTp = relTw + 4096;
  unsigned short* wtap = xTp + (size_t)NB * XPSTRIDE;
  unsigned short* wqbf = wtap + 589824;
  unsigned short* woutbf = wqbf + 327680;

  prep_all<<<dim3(5056), 256, 0, stream>>>(x, wconv, wqkv, wout, krh, krw,
                                           wtap, wqbf, woutbf, relTh, relTw, xTp);
  qkv_mfma<<<dim3(20, 16, NB), 256, 0, stream>>>(xTp, wqbf, qbf, kbf, vbf);
  conv_mfma<<<dim3(4, 16, NB), 256, 0, stream>>>(xTp, wtap, out);
  attn_kernel<<<dim3(512), 256, 0, stream>>>(qbf, kbf, vbf, relTh, relTw, abf);
  proj_mfma<<<dim3(4, 16, NB), 256, 0, stream>>>(abf, woutbf, out);
}